// Round 16
// baseline (185.246 us; speedup 1.0000x reference)
//
#include <hip/hip_runtime.h>
#include <hip/hip_bf16.h>
#include <cstdint>

// SpatialAttention: x[1,256,16,16,16] -> qkv(768x256) -> 8-head attn(d=32, n=4096) -> proj(256x256)+bias
// ws (u16 units): qT[8][4096][32] @0 (pre-scaled by SCALE*log2e), kT @1M, vv[8][32][4096] @2M,
//                 aout[4096][256] @3M, xT[4096][256] @4M, wqb[768][256] @5M, wob[256][256] @5M+192K

typedef __bf16 bf16x8 __attribute__((ext_vector_type(8)));
typedef float f32x4 __attribute__((ext_vector_type(4)));
typedef float f32x16 __attribute__((ext_vector_type(16)));
typedef unsigned int u32;
typedef unsigned short u16;
typedef u32 u32x4v __attribute__((ext_vector_type(4)));
typedef u32 u32x2v __attribute__((ext_vector_type(2)));

#define MFMA16(a, b, c) __builtin_amdgcn_mfma_f32_16x16x32_bf16(a, b, c, 0, 0, 0)
#define MFMA32(a, b, c) __builtin_amdgcn_mfma_f32_32x32x16_bf16(a, b, c, 0, 0, 0)

#if __has_builtin(__builtin_amdgcn_exp2f)
#define EXP2(x) __builtin_amdgcn_exp2f(x)
#else
#define EXP2(x) exp2f(x)
#endif

__device__ __forceinline__ u16 f2bf(float f) {
  __bf16 b = (__bf16)f;
  return __builtin_bit_cast(u16, b);
}
__device__ __forceinline__ u32 pk2(float a, float b) {
  return (u32)f2bf(a) | ((u32)f2bf(b) << 16);
}
__device__ __forceinline__ bf16x8 ldfrag(const u16* p) {
  return __builtin_bit_cast(bf16x8, *(const u32x4v*)p);
}
__device__ __forceinline__ void gload_lds16(const void* g, void* l) {
  __builtin_amdgcn_global_load_lds((const __attribute__((address_space(1))) u32*)g,
                                   (__attribute__((address_space(3))) u32*)l, 16, 0, 0);
}
// v_permlane32_swap_b32: a = {a.lo, b.lo}, b = {a.hi, b.hi}
__device__ __forceinline__ void plswap(u32& a, u32& b) {
  asm("v_permlane32_swap_b32 %0, %1" : "+v"(a), "+v"(b));
}
__device__ __forceinline__ f32x16 zero16() {
  f32x16 z;
#pragma unroll
  for (int i = 0; i < 16; ++i) z[i] = 0.0f;
  return z;
}

#if __has_builtin(__builtin_amdgcn_fdot2_f32_bf16)
typedef __bf16 bf16x2 __attribute__((ext_vector_type(2)));
__device__ __forceinline__ float dot2one(u32 pk, float acc) {
  const u32 one2 = 0x3F803F80u;  // {1.0bf, 1.0bf}
  return __builtin_amdgcn_fdot2_f32_bf16(__builtin_bit_cast(bf16x2, pk),
                                         __builtin_bit_cast(bf16x2, one2), acc, false);
}
#define LSUM4(LSUM, PK0, PK1, PK2, PK3) \
  LSUM = dot2one(PK0, LSUM);            \
  LSUM = dot2one(PK1, LSUM);            \
  LSUM = dot2one(PK2, LSUM);            \
  LSUM = dot2one(PK3, LSUM);
#define LSUM_F32(LSUM, ...)
#else
#define LSUM4(LSUM, PK0, PK1, PK2, PK3)
#define LSUM_F32(LSUM, P0, P1, P2, P3, P4, P5, P6, P7) \
  LSUM += ((P0 + P1) + (P2 + P3)) + ((P4 + P5) + (P6 + P7));
#endif

// ---------------- K0: prep — x transpose to xT bf16, w_qkv->bf16 (q-scaled), w_out->bf16 --------
// grid 320 x 256: blocks 0..255 transpose, 256..303 w_qkv, 304..319 w_out
__global__ __launch_bounds__(256) void prep(const float* __restrict__ x,
                                            const float* __restrict__ wq,
                                            const float* __restrict__ wo,
                                            u16* __restrict__ xT, u16* __restrict__ wqb,
                                            u16* __restrict__ wob) {
  const int b = blockIdx.x;
  const int t = threadIdx.x;
  if (b < 256) {
    __shared__ u16 tile[64][72];
    const int n0 = (b & 63) * 64, c0 = (b >> 6) * 64;
#pragma unroll
    for (int r = 0; r < 4; ++r) {
      int c = r * 16 + (t >> 4);
      int n4 = (t & 15) << 2;
      float4 v = *(const float4*)(x + (size_t)(c0 + c) * 4096 + n0 + n4);
      tile[n4 + 0][c] = f2bf(v.x);
      tile[n4 + 1][c] = f2bf(v.y);
      tile[n4 + 2][c] = f2bf(v.z);
      tile[n4 + 3][c] = f2bf(v.w);
    }
    __syncthreads();
#pragma unroll
    for (int r2 = 0; r2 < 2; ++r2) {
      int n = r2 * 32 + (t >> 3);
      int c8 = (t & 7) << 3;
      u32x4v o;
#pragma unroll
      for (int j = 0; j < 4; ++j)
        o[j] = (u32)tile[n][c8 + 2 * j] | ((u32)tile[n][c8 + 2 * j + 1] << 16);
      *(u32x4v*)(xT + (size_t)(n0 + n) * 256 + c0 + c8) = o;
    }
  } else if (b < 304) {
    int base = (b - 256) * 4096;
#pragma unroll
    for (int r = 0; r < 4; ++r) {
      int i = base + r * 1024 + t * 4;
      float4 v = *(const float4*)(wq + i);
      float sc = (i < 65536) ? 0.2550349f : 1.0f;  // q rows: 32^-0.5 * log2(e)
      u32x2v pkd;
      pkd.x = pk2(v.x * sc, v.y * sc);
      pkd.y = pk2(v.z * sc, v.w * sc);
      *(u32x2v*)(wqb + i) = pkd;
    }
  } else {
    int base = (b - 304) * 4096;
#pragma unroll
    for (int r = 0; r < 4; ++r) {
      int i = base + r * 1024 + t * 4;
      float4 v = *(const float4*)(wo + i);
      u32x2v pkd;
      pkd.x = pk2(v.x, v.y);
      pkd.y = pk2(v.z, v.w);
      *(u32x2v*)(wob + i) = pkd;
    }
  }
}

// ---------------- K1: qkv = wqb(768x256) @ xT^T, double-buffered counted-vmcnt staging ----------
// grid (64 nb, 12 ob), 256 thr = 4 waves: wm=w&1, wn=w>>1 -> 32o x 32n per wave
__global__ __launch_bounds__(256) void qkv_gemm(const u16* __restrict__ xT,
                                                const u16* __restrict__ wqb,
                                                u16* __restrict__ qT, u16* __restrict__ kT,
                                                u16* __restrict__ vv) {
  __shared__ __align__(16) u16 Al[2][64 * 64];
  __shared__ __align__(16) u16 Bl[2][64 * 64];
  const int t = threadIdx.x;
  const int lane = t & 63, w = t >> 6;
  const int wm = w & 1, wn = w >> 1;
  const int o0 = blockIdx.y * 64, n0 = blockIdx.x * 64;
  const int lr = lane & 15, lg = lane >> 4;
  const int srow = lane >> 3, sslot = lane & 7;
  f32x4 acc[2][2];
#pragma unroll
  for (int i = 0; i < 2; ++i)
#pragma unroll
    for (int j = 0; j < 2; ++j)
#pragma unroll
      for (int r = 0; r < 4; ++r) acc[i][j][r] = 0.0f;

#define QKV_STAGE(KI, BUF)                                                                   \
  do {                                                                                       \
    _Pragma("unroll") for (int rnd = 0; rnd < 2; ++rnd) {                                    \
      int row = rnd * 32 + w * 8 + srow;                                                     \
      gload_lds16(wqb + (size_t)(o0 + row) * 256 + (KI) * 64 + ((sslot ^ (row & 7)) << 3),   \
                  (void*)(&Al[BUF][rnd * 2048 + w * 512]));                                  \
      gload_lds16(xT + (size_t)(n0 + row) * 256 + (KI) * 64 + ((sslot ^ (row & 7)) << 3),    \
                  (void*)(&Bl[BUF][rnd * 2048 + w * 512]));                                  \
    }                                                                                        \
  } while (0)

  QKV_STAGE(0, 0);
#pragma unroll
  for (int ki = 0; ki < 4; ++ki) {
    if (ki < 3) {
      QKV_STAGE(ki + 1, (ki + 1) & 1);
      asm volatile("s_waitcnt vmcnt(4)" ::: "memory");  // tile ki's 4 loads landed
    } else {
      asm volatile("s_waitcnt vmcnt(0)" ::: "memory");
    }
    __builtin_amdgcn_sched_barrier(0);
    __builtin_amdgcn_s_barrier();
    asm volatile("" ::: "memory");
    const u16* Ab = &Al[ki & 1][0];
    const u16* Bb = &Bl[ki & 1][0];
#pragma unroll
    for (int kk = 0; kk < 2; ++kk) {
      bf16x8 af[2], bf_[2];
#pragma unroll
      for (int mi = 0; mi < 2; ++mi) {
        int row = wm * 32 + mi * 16 + lr;
        af[mi] = ldfrag(&Ab[row * 64 + ((kk * 32 + lg * 8) ^ ((row & 7) << 3))]);
      }
#pragma unroll
      for (int ni = 0; ni < 2; ++ni) {
        int row = wn * 32 + ni * 16 + lr;
        bf_[ni] = ldfrag(&Bb[row * 64 + ((kk * 32 + lg * 8) ^ ((row & 7) << 3))]);
      }
#pragma unroll
      for (int mi = 0; mi < 2; ++mi)
#pragma unroll
        for (int ni = 0; ni < 2; ++ni) acc[mi][ni] = MFMA16(af[mi], bf_[ni], acc[mi][ni]);
    }
    asm volatile("s_waitcnt lgkmcnt(0)" ::: "memory");
    __builtin_amdgcn_sched_barrier(0);
    __builtin_amdgcn_s_barrier();  // buffer (ki&1) now reusable by next stage
    asm volatile("" ::: "memory");
  }
  // epilogue: D[o][n]; col n = lr, rows o = obase + r; scatter to q/k/v layouts
#pragma unroll
  for (int mi = 0; mi < 2; ++mi) {
#pragma unroll
    for (int ni = 0; ni < 2; ++ni) {
      int obase = o0 + wm * 32 + mi * 16 + lg * 4;
      int n = n0 + wn * 32 + ni * 16 + lr;
      int part = obase >> 8;
      int oin = obase & 255;
      int h = oin >> 5, c0 = oin & 31;
      if (part == 0) {
        u32x2v pv;
        pv.x = pk2(acc[mi][ni][0], acc[mi][ni][1]);
        pv.y = pk2(acc[mi][ni][2], acc[mi][ni][3]);
        *(u32x2v*)(qT + ((size_t)h * 4096 + n) * 32 + c0) = pv;
      } else if (part == 1) {
        u32x2v pv;
        pv.x = pk2(acc[mi][ni][0], acc[mi][ni][1]);
        pv.y = pk2(acc[mi][ni][2], acc[mi][ni][3]);
        *(u32x2v*)(kT + ((size_t)h * 4096 + n) * 32 + c0) = pv;
      } else {
#pragma unroll
        for (int r = 0; r < 4; ++r)
          vv[((size_t)h * 32 + c0 + r) * 4096 + n] = f2bf(acc[mi][ni][r]);
      }
    }
  }
}

// ---------------- K2: fused flash attention, P-state pipeline (PV -> QK -> loads -> exp) --------
// 1D grid 512: h = bid & 7 (XCD pinning), qb = bid >> 3; 8 waves; wave s: 64 q x 512 kv, 16 tiles
// Stage T: PV(T) from stored P-state (dies) | QK(T+1) from kn (sT born) | reload kn=K(T+2),
// V(T+2) BEFORE the exp block (~280cy cover) | EXPPACK sT -> P-state(T+1) (sT dies in-stage).
// setprio around the 8-MFMA cluster is load-bearing (R13 A/B: removal -> spill, +14us).

// exp + pack + cross-half swap: ST (f32x16) -> F1 (j 0..15), F2 (j 16..31); accumulates LSUM
#define EXPPACK(ST, F1, F2, LSUM)                                               \
  do {                                                                          \
    float p0_ = EXP2(ST[0]), p1_ = EXP2(ST[1]);                                 \
    float p2_ = EXP2(ST[2]), p3_ = EXP2(ST[3]);                                 \
    float p4_ = EXP2(ST[4]), p5_ = EXP2(ST[5]);                                 \
    float p6_ = EXP2(ST[6]), p7_ = EXP2(ST[7]);                                 \
    u32 k0_ = pk2(p0_, p1_), k1_ = pk2(p2_, p3_);                               \
    u32 k2_ = pk2(p4_, p5_), k3_ = pk2(p6_, p7_);                               \
    LSUM4(LSUM, k0_, k1_, k2_, k3_)                                             \
    LSUM_F32(LSUM, p0_, p1_, p2_, p3_, p4_, p5_, p6_, p7_)                      \
    u32 ax_ = k0_, bx_ = k2_;                                                   \
    plswap(ax_, bx_);                                                           \
    u32 ay_ = k1_, by_ = k3_;                                                   \
    plswap(ay_, by_);                                                           \
    F1.x = ax_; F1.y = ay_; F1.z = bx_; F1.w = by_;                             \
    float q0_ = EXP2(ST[8]), q1_ = EXP2(ST[9]);                                 \
    float q2_ = EXP2(ST[10]), q3_ = EXP2(ST[11]);                               \
    float q4_ = EXP2(ST[12]), q5_ = EXP2(ST[13]);                               \
    float q6_ = EXP2(ST[14]), q7_ = EXP2(ST[15]);                               \
    u32 m0_ = pk2(q0_, q1_), m1_ = pk2(q2_, q3_);                               \
    u32 m2_ = pk2(q4_, q5_), m3_ = pk2(q6_, q7_);                               \
    LSUM4(LSUM, m0_, m1_, m2_, m3_)                                             \
    LSUM_F32(LSUM, q0_, q1_, q2_, q3_, q4_, q5_, q6_, q7_)                      \
    u32 cx_ = m0_, dx_ = m2_;                                                   \
    plswap(cx_, dx_);                                                           \
    u32 cy_ = m1_, dy_ = m3_;                                                   \
    plswap(cy_, dy_);                                                           \
    F2.x = cx_; F2.y = cy_; F2.z = dx_; F2.w = dy_;                             \
  } while (0)

#define STAGE_N(T, VC0, VC1)                                                    \
  do {                                                                          \
    __builtin_amdgcn_s_setprio(1);                                              \
    oacc0 = MFMA32(VC0, __builtin_bit_cast(bf16x8, fA1), oacc0);                \
    oacc0 = MFMA32(VC1, __builtin_bit_cast(bf16x8, fA2), oacc0);                \
    oacc1 = MFMA32(VC0, __builtin_bit_cast(bf16x8, fB1), oacc1);                \
    oacc1 = MFMA32(VC1, __builtin_bit_cast(bf16x8, fB2), oacc1);                \
    if ((T) + 1 < 16) {                                                         \
      sTa = zero16();                                                           \
      sTa = MFMA32(kn0, qf00, sTa);                                             \
      sTa = MFMA32(kn1, qf01, sTa);                                             \
      sTb = zero16();                                                           \
      sTb = MFMA32(kn0, qf10, sTb);                                             \
      sTb = MFMA32(kn1, qf11, sTb);                                             \
    }                                                                           \
    __builtin_amdgcn_s_setprio(0);                                              \
    if ((T) + 2 < 16) {                                                         \
      kn0 = ldfrag(kp0 + ((T) + 2) * 1024);                                     \
      kn1 = ldfrag(kp0 + ((T) + 2) * 1024 + 16);                                \
      VC0 = ldfrag(vp0 + ((T) + 2) * 32);                                       \
      VC1 = ldfrag(vp0 + ((T) + 2) * 32 + 16);                                  \
    }                                                                           \
    if ((T) + 1 < 16) {                                                         \
      EXPPACK(sTa, fA1, fA2, lsum0);                                            \
      EXPPACK(sTb, fB1, fB2, lsum1);                                            \
    }                                                                           \
  } while (0)

__global__ __launch_bounds__(512, 4) void attn_fused(const u16* __restrict__ qT,
                                                     const u16* __restrict__ kT,
                                                     const u16* __restrict__ vv,
                                                     u16* __restrict__ aout) {
  __shared__ float pbuf[8 * 32 * 66];  // [8 s][32 c][64 i + 2 pad]
  __shared__ float lbuf[8 * 64];       // [8 s][64 i]
  const int tid = threadIdx.x;
  const int lane = tid & 63, s = tid >> 6;
  const int h = blockIdx.x & 7, qb = blockIdx.x >> 3;  // h -> XCD pinning
  const int l31 = lane & 31, lh = lane >> 5;
  const u16* qTh = qT + (size_t)h * (4096 * 32);
  const u16* kTh = kT + (size_t)h * (4096 * 32);
  const u16* vh = vv + (size_t)h * (32 * 4096);

  // Q fragments (B-operand: col i = l31, k c = m*16+lh*8+e); pre-scaled by SCALE*log2e
  const int i0 = qb * 64 + l31;
  bf16x8 qf00 = ldfrag(qTh + (size_t)i0 * 32 + lh * 8);
  bf16x8 qf01 = ldfrag(qTh + (size_t)i0 * 32 + 16 + lh * 8);
  bf16x8 qf10 = ldfrag(qTh + (size_t)(i0 + 32) * 32 + lh * 8);
  bf16x8 qf11 = ldfrag(qTh + (size_t)(i0 + 32) * 32 + 16 + lh * 8);

  f32x16 oacc0 = zero16(), oacc1 = zero16();
  float lsum0 = 0.0f, lsum1 = 0.0f;
  const int kvbase = s * 512;

  // per-tile bases: K tile tt at kp0 + tt*1024 (u16), V tile tt at vp0 + tt*32
  const u16* kp0 = kTh + (size_t)(kvbase + l31) * 32 + lh * 8;
  const u16* vp0 = vh + (size_t)l31 * 4096 + kvbase + lh * 8;

  // prologue: K(0) (transient), V(0), K(1), V(1); compute P-state for tile 0
  bf16x8 kc0 = ldfrag(kp0), kc1 = ldfrag(kp0 + 16);
  bf16x8 vfa0 = ldfrag(vp0), vfa1 = ldfrag(vp0 + 16);
  bf16x8 kn0 = ldfrag(kp0 + 1024), kn1 = ldfrag(kp0 + 1024 + 16);
  bf16x8 vfb0 = ldfrag(vp0 + 32), vfb1 = ldfrag(vp0 + 32 + 16);
  f32x16 sTa = zero16(), sTb = zero16();
  __builtin_amdgcn_s_setprio(1);
  sTa = MFMA32(kc0, qf00, sTa);
  sTa = MFMA32(kc1, qf01, sTa);
  sTb = MFMA32(kc0, qf10, sTb);
  sTb = MFMA32(kc1, qf11, sTb);
  __builtin_amdgcn_s_setprio(0);
  u32x4v fA1, fA2, fB1, fB2;
  EXPPACK(sTa, fA1, fA2, lsum0);
  EXPPACK(sTb, fB1, fB2, lsum1);

#pragma unroll
  for (int tt = 0; tt < 16; tt += 2) {
    STAGE_N(tt, vfa0, vfa1);      // even tile: V in vfa, refilled with V(tt+2)
    STAGE_N(tt + 1, vfb0, vfb1);  // odd tile: V in vfb, refilled with V(tt+3)
  }

  // per-wave partials to LDS (disjoint slots, no atomics)
  float ls0 = lsum0 + __shfl_xor(lsum0, 32, 64);
  float ls1 = lsum1 + __shfl_xor(lsum1, 32, 64);
#pragma unroll
  for (int r = 0; r < 16; ++r) {
    int c = (r & 3) + 8 * (r >> 2) + 4 * lh;
    pbuf[(s * 32 + c) * 66 + l31] = oacc0[r];
    pbuf[(s * 32 + c) * 66 + 32 + l31] = oacc1[r];
  }
  lbuf[s * 64 + l31] = ls0;
  lbuf[s * 64 + 32 + l31] = ls1;
  __syncthreads();

  // reduce 8 kv-split partials, normalize, store attnout[n][256] bf16
  {
    int i = tid >> 3, c0 = (tid & 7) << 2;
    float lt = 0.0f;
#pragma unroll
    for (int ss = 0; ss < 8; ++ss) lt += lbuf[ss * 64 + i];
    float inv = 1.0f / lt;
    float a[4];
#pragma unroll
    for (int cc = 0; cc < 4; ++cc) a[cc] = 0.0f;
#pragma unroll
    for (int ss = 0; ss < 8; ++ss)
#pragma unroll
      for (int cc = 0; cc < 4; ++cc) a[cc] += pbuf[(ss * 32 + c0 + cc) * 66 + i];
    u32x2v ov;
    ov.x = pk2(a[0] * inv, a[1] * inv);
    ov.y = pk2(a[2] * inv, a[3] * inv);
    *(u32x2v*)(aout + (size_t)(qb * 64 + i) * 256 + h * 32 + c0) = ov;
  }
}

// ---------------- K3: out = wob(256x256) @ attnout^T + b, double-buffered counted-vmcnt --------
// grid (64 nb, 4 db); 256 thr = 4 waves, wave w -> d-strip w*16; same 2-phase pipeline as K1
__global__ __launch_bounds__(256) void out_proj(const u16* __restrict__ wob,
                                                const float* __restrict__ bo,
                                                const u16* __restrict__ aout,
                                                float* __restrict__ out) {
  __shared__ __align__(16) u16 Al[2][64 * 64];
  __shared__ __align__(16) u16 Bl[2][64 * 64];
  const int t = threadIdx.x;
  const int lane = t & 63, w = t >> 6;
  const int n0 = blockIdx.x * 64, d0 = blockIdx.y * 64;
  const int lr = lane & 15, lg = lane >> 4;
  const int srow = lane >> 3, sslot = lane & 7;
  f32x4 acc[4];
#pragma unroll
  for (int ni = 0; ni < 4; ++ni)
#pragma unroll
    for (int r = 0; r < 4; ++r) acc[ni][r] = 0.0f;

#define PROJ_STAGE(KI, BUF)                                                                  \
  do {                                                                                       \
    _Pragma("unroll") for (int rnd = 0; rnd < 2; ++rnd) {                                    \
      int row = rnd * 32 + w * 8 + srow;                                                     \
      gload_lds16(wob + (size_t)(d0 + row) * 256 + (KI) * 64 + ((sslot ^ (row & 7)) << 3),   \
                  (void*)(&Al[BUF][rnd * 2048 + w * 512]));                                  \
      gload_lds16(aout + (size_t)(n0 + row) * 256 + (KI) * 64 + ((sslot ^ (row & 7)) << 3),  \
                  (void*)(&Bl[BUF][rnd * 2048 + w * 512]));                                  \
    }                                                                                        \
  } while (0)

  PROJ_STAGE(0, 0);
#pragma unroll
  for (int ki = 0; ki < 4; ++ki) {
    if (ki < 3) {
      PROJ_STAGE(ki + 1, (ki + 1) & 1);
      asm volatile("s_waitcnt vmcnt(4)" ::: "memory");
    } else {
      asm volatile("s_waitcnt vmcnt(0)" ::: "memory");
    }
    __builtin_amdgcn_sched_barrier(0);
    __builtin_amdgcn_s_barrier();
    asm volatile("" ::: "memory");
    const u16* Ab = &Al[ki & 1][0];
    const u16* Bb = &Bl[ki & 1][0];
#pragma unroll
    for (int kk = 0; kk < 2; ++kk) {
      int arow = w * 16 + lr;
      bf16x8 af = ldfrag(&Ab[arow * 64 + ((kk * 32 + lg * 8) ^ ((arow & 7) << 3))]);
#pragma unroll
      for (int ni = 0; ni < 4; ++ni) {
        int brow = ni * 16 + lr;
        bf16x8 bfr = ldfrag(&Bb[brow * 64 + ((kk * 32 + lg * 8) ^ ((brow & 7) << 3))]);
        acc[ni] = MFMA16(af, bfr, acc[ni]);
      }
    }
    asm volatile("s_waitcnt lgkmcnt(0)" ::: "memory");
    __builtin_amdgcn_sched_barrier(0);
    __builtin_amdgcn_s_barrier();
    asm volatile("" ::: "memory");
  }
#pragma unroll
  for (int ni = 0; ni < 4; ++ni) {
    int n = n0 + ni * 16 + lr;
#pragma unroll
    for (int r = 0; r < 4; ++r) {
      int d = d0 + w * 16 + lg * 4 + r;
      out[(size_t)d * 4096 + n] = acc[ni][r] + bo[d];
    }
  }
}

extern "C" void kernel_launch(void* const* d_in, const int* in_sizes, int n_in,
                              void* d_out, int out_size, void* d_ws, size_t ws_size,
                              hipStream_t stream) {
  (void)in_sizes; (void)n_in; (void)out_size; (void)ws_size;
  const float* x = (const float*)d_in[0];
  const float* wqkv = (const float*)d_in[1];
  const float* wout = (const float*)d_in[2];
  const float* bout = (const float*)d_in[3];
  float* out = (float*)d_out;
  u16* qT = (u16*)d_ws;            // [8][4096][32]
  u16* kT = qT + 8 * 4096 * 32;    // [8][4096][32]
  u16* vv = kT + 8 * 4096 * 32;    // [8][32][4096]
  u16* aout = vv + 8 * 32 * 4096;  // [4096][256]
  u16* xT = aout + 4096 * 256;     // [4096][256]
  u16* wqb = xT + 4096 * 256;      // [768][256]
  u16* wob = wqb + 768 * 256;      // [256][256]

  prep<<<320, 256, 0, stream>>>(x, wqkv, wout, xT, wqb, wob);
  qkv_gemm<<<dim3(64, 12), 256, 0, stream>>>(xT, wqb, qT, kT, vv);
  attn_fused<<<512, 512, 0, stream>>>(qT, kT, vv, aout);
  out_proj<<<dim3(64, 4), 256, 0, stream>>>(wob, bout, aout, out);
}

// Round 17
// 48.192 us; speedup vs baseline: 3.8439x; 3.8439x over previous
//
#include <hip/hip_runtime.h>
#include <hip/hip_bf16.h>
#include <cstdint>

// SpatialAttention: x[1,256,16,16,16] -> qkv(768x256) -> 8-head attn(d=32, n=4096) -> proj(256x256)+bias
// ws (u16 units): qT[8][4096][32] @0 (pre-scaled by SCALE*log2e), kT @1M, vv[8][32][4096] @2M,
//                 aout[4096][256] @3M, xT[4096][256] @4M, wqb[768][256] @5M, wob[256][256] @5M+192K

typedef __bf16 bf16x8 __attribute__((ext_vector_type(8)));
typedef float f32x4 __attribute__((ext_vector_type(4)));
typedef float f32x16 __attribute__((ext_vector_type(16)));
typedef unsigned int u32;
typedef unsigned short u16;
typedef u32 u32x4v __attribute__((ext_vector_type(4)));
typedef u32 u32x2v __attribute__((ext_vector_type(2)));

#define MFMA16(a, b, c) __builtin_amdgcn_mfma_f32_16x16x32_bf16(a, b, c, 0, 0, 0)
#define MFMA32(a, b, c) __builtin_amdgcn_mfma_f32_32x32x16_bf16(a, b, c, 0, 0, 0)

#if __has_builtin(__builtin_amdgcn_exp2f)
#define EXP2(x) __builtin_amdgcn_exp2f(x)
#else
#define EXP2(x) exp2f(x)
#endif

__device__ __forceinline__ u16 f2bf(float f) {
  __bf16 b = (__bf16)f;
  return __builtin_bit_cast(u16, b);
}
__device__ __forceinline__ u32 pk2(float a, float b) {
  return (u32)f2bf(a) | ((u32)f2bf(b) << 16);
}
__device__ __forceinline__ bf16x8 ldfrag(const u16* p) {
  return __builtin_bit_cast(bf16x8, *(const u32x4v*)p);
}
__device__ __forceinline__ void gload_lds16(const void* g, void* l) {
  __builtin_amdgcn_global_load_lds((const __attribute__((address_space(1))) u32*)g,
                                   (__attribute__((address_space(3))) u32*)l, 16, 0, 0);
}
// v_permlane32_swap_b32: a = {a.lo, b.lo}, b = {a.hi, b.hi}
__device__ __forceinline__ void plswap(u32& a, u32& b) {
  asm("v_permlane32_swap_b32 %0, %1" : "+v"(a), "+v"(b));
}
__device__ __forceinline__ f32x16 zero16() {
  f32x16 z;
#pragma unroll
  for (int i = 0; i < 16; ++i) z[i] = 0.0f;
  return z;
}

#if __has_builtin(__builtin_amdgcn_fdot2_f32_bf16)
typedef __bf16 bf16x2 __attribute__((ext_vector_type(2)));
__device__ __forceinline__ float dot2one(u32 pk, float acc) {
  const u32 one2 = 0x3F803F80u;  // {1.0bf, 1.0bf}
  return __builtin_amdgcn_fdot2_f32_bf16(__builtin_bit_cast(bf16x2, pk),
                                         __builtin_bit_cast(bf16x2, one2), acc, false);
}
#define LSUM4(LSUM, PK0, PK1, PK2, PK3) \
  LSUM = dot2one(PK0, LSUM);            \
  LSUM = dot2one(PK1, LSUM);            \
  LSUM = dot2one(PK2, LSUM);            \
  LSUM = dot2one(PK3, LSUM);
#define LSUM_F32(LSUM, ...)
#else
#define LSUM4(LSUM, PK0, PK1, PK2, PK3)
#define LSUM_F32(LSUM, P0, P1, P2, P3, P4, P5, P6, P7) \
  LSUM += ((P0 + P1) + (P2 + P3)) + ((P4 + P5) + (P6 + P7));
#endif

// ---------------- K0: prep — x transpose to xT bf16, w_qkv->bf16 (q-scaled), w_out->bf16 --------
// grid 320 x 256: blocks 0..255 transpose, 256..303 w_qkv, 304..319 w_out
__global__ __launch_bounds__(256) void prep(const float* __restrict__ x,
                                            const float* __restrict__ wq,
                                            const float* __restrict__ wo,
                                            u16* __restrict__ xT, u16* __restrict__ wqb,
                                            u16* __restrict__ wob) {
  const int b = blockIdx.x;
  const int t = threadIdx.x;
  if (b < 256) {
    __shared__ u16 tile[64][72];
    const int n0 = (b & 63) * 64, c0 = (b >> 6) * 64;
#pragma unroll
    for (int r = 0; r < 4; ++r) {
      int c = r * 16 + (t >> 4);
      int n4 = (t & 15) << 2;
      float4 v = *(const float4*)(x + (size_t)(c0 + c) * 4096 + n0 + n4);
      tile[n4 + 0][c] = f2bf(v.x);
      tile[n4 + 1][c] = f2bf(v.y);
      tile[n4 + 2][c] = f2bf(v.z);
      tile[n4 + 3][c] = f2bf(v.w);
    }
    __syncthreads();
#pragma unroll
    for (int r2 = 0; r2 < 2; ++r2) {
      int n = r2 * 32 + (t >> 3);
      int c8 = (t & 7) << 3;
      u32x4v o;
#pragma unroll
      for (int j = 0; j < 4; ++j)
        o[j] = (u32)tile[n][c8 + 2 * j] | ((u32)tile[n][c8 + 2 * j + 1] << 16);
      *(u32x4v*)(xT + (size_t)(n0 + n) * 256 + c0 + c8) = o;
    }
  } else if (b < 304) {
    int base = (b - 256) * 4096;
#pragma unroll
    for (int r = 0; r < 4; ++r) {
      int i = base + r * 1024 + t * 4;
      float4 v = *(const float4*)(wq + i);
      float sc = (i < 65536) ? 0.2550349f : 1.0f;  // q rows: 32^-0.5 * log2(e)
      u32x2v pkd;
      pkd.x = pk2(v.x * sc, v.y * sc);
      pkd.y = pk2(v.z * sc, v.w * sc);
      *(u32x2v*)(wqb + i) = pkd;
    }
  } else {
    int base = (b - 304) * 4096;
#pragma unroll
    for (int r = 0; r < 4; ++r) {
      int i = base + r * 1024 + t * 4;
      float4 v = *(const float4*)(wo + i);
      u32x2v pkd;
      pkd.x = pk2(v.x, v.y);
      pkd.y = pk2(v.z, v.w);
      *(u32x2v*)(wob + i) = pkd;
    }
  }
}

// ---------------- K1: qkv = wqb(768x256) @ xT^T, double-buffered counted-vmcnt staging ----------
// grid (64 nb, 12 ob), 256 thr = 4 waves: wm=w&1, wn=w>>1 -> 32o x 32n per wave
// 2-phase pipeline: issue tile t+1's loads, s_waitcnt vmcnt(4) (tile t landed, t+1 in flight),
// raw s_barrier, compute tile t, barrier (protect buffer overwrite). No full drain in loop.
__global__ __launch_bounds__(256) void qkv_gemm(const u16* __restrict__ xT,
                                                const u16* __restrict__ wqb,
                                                u16* __restrict__ qT, u16* __restrict__ kT,
                                                u16* __restrict__ vv) {
  __shared__ __align__(16) u16 Al[2][64 * 64];
  __shared__ __align__(16) u16 Bl[2][64 * 64];
  const int t = threadIdx.x;
  const int lane = t & 63, w = t >> 6;
  const int wm = w & 1, wn = w >> 1;
  const int o0 = blockIdx.y * 64, n0 = blockIdx.x * 64;
  const int lr = lane & 15, lg = lane >> 4;
  const int srow = lane >> 3, sslot = lane & 7;
  f32x4 acc[2][2];
#pragma unroll
  for (int i = 0; i < 2; ++i)
#pragma unroll
    for (int j = 0; j < 2; ++j)
#pragma unroll
      for (int r = 0; r < 4; ++r) acc[i][j][r] = 0.0f;

#define QKV_STAGE(KI, BUF)                                                                   \
  do {                                                                                       \
    _Pragma("unroll") for (int rnd = 0; rnd < 2; ++rnd) {                                    \
      int row = rnd * 32 + w * 8 + srow;                                                     \
      gload_lds16(wqb + (size_t)(o0 + row) * 256 + (KI) * 64 + ((sslot ^ (row & 7)) << 3),   \
                  (void*)(&Al[BUF][rnd * 2048 + w * 512]));                                  \
      gload_lds16(xT + (size_t)(n0 + row) * 256 + (KI) * 64 + ((sslot ^ (row & 7)) << 3),    \
                  (void*)(&Bl[BUF][rnd * 2048 + w * 512]));                                  \
    }                                                                                        \
  } while (0)

  QKV_STAGE(0, 0);
#pragma unroll
  for (int ki = 0; ki < 4; ++ki) {
    if (ki < 3) {
      QKV_STAGE(ki + 1, (ki + 1) & 1);
      asm volatile("s_waitcnt vmcnt(4)" ::: "memory");  // tile ki's 4 loads landed
    } else {
      asm volatile("s_waitcnt vmcnt(0)" ::: "memory");
    }
    __builtin_amdgcn_sched_barrier(0);
    __builtin_amdgcn_s_barrier();
    asm volatile("" ::: "memory");
    const u16* Ab = &Al[ki & 1][0];
    const u16* Bb = &Bl[ki & 1][0];
#pragma unroll
    for (int kk = 0; kk < 2; ++kk) {
      bf16x8 af[2], bf_[2];
#pragma unroll
      for (int mi = 0; mi < 2; ++mi) {
        int row = wm * 32 + mi * 16 + lr;
        af[mi] = ldfrag(&Ab[row * 64 + ((kk * 32 + lg * 8) ^ ((row & 7) << 3))]);
      }
#pragma unroll
      for (int ni = 0; ni < 2; ++ni) {
        int row = wn * 32 + ni * 16 + lr;
        bf_[ni] = ldfrag(&Bb[row * 64 + ((kk * 32 + lg * 8) ^ ((row & 7) << 3))]);
      }
#pragma unroll
      for (int mi = 0; mi < 2; ++mi)
#pragma unroll
        for (int ni = 0; ni < 2; ++ni) acc[mi][ni] = MFMA16(af[mi], bf_[ni], acc[mi][ni]);
    }
    asm volatile("s_waitcnt lgkmcnt(0)" ::: "memory");
    __builtin_amdgcn_sched_barrier(0);
    __builtin_amdgcn_s_barrier();  // buffer (ki&1) now reusable by next stage
    asm volatile("" ::: "memory");
  }
  // epilogue: D[o][n]; col n = lr, rows o = obase + r; scatter to q/k/v layouts
#pragma unroll
  for (int mi = 0; mi < 2; ++mi) {
#pragma unroll
    for (int ni = 0; ni < 2; ++ni) {
      int obase = o0 + wm * 32 + mi * 16 + lg * 4;
      int n = n0 + wn * 32 + ni * 16 + lr;
      int part = obase >> 8;
      int oin = obase & 255;
      int h = oin >> 5, c0 = oin & 31;
      if (part == 0) {
        u32x2v pv;
        pv.x = pk2(acc[mi][ni][0], acc[mi][ni][1]);
        pv.y = pk2(acc[mi][ni][2], acc[mi][ni][3]);
        *(u32x2v*)(qT + ((size_t)h * 4096 + n) * 32 + c0) = pv;
      } else if (part == 1) {
        u32x2v pv;
        pv.x = pk2(acc[mi][ni][0], acc[mi][ni][1]);
        pv.y = pk2(acc[mi][ni][2], acc[mi][ni][3]);
        *(u32x2v*)(kT + ((size_t)h * 4096 + n) * 32 + c0) = pv;
      } else {
#pragma unroll
        for (int r = 0; r < 4; ++r)
          vv[((size_t)h * 32 + c0 + r) * 4096 + n] = f2bf(acc[mi][ni][r]);
      }
    }
  }
}

// ---------------- K2: fused flash attention, sT-pipelined (QK one tile ahead), named dbuf -------
// 1D grid 512: h = bid & 7 (XCD pinning), qb = bid >> 3; 8 waves; wave s: 64 q x 512 kv, 16 tiles
// setprio fences around MFMA clusters are load-bearing: they bound scheduler regions and keep
// register pressure under the allocation (R13 A/B: removing them -> VGPR 64 + 41MB spill, +14us).
// The sT-early stage shape is also load-bearing (R16: moving EXPPACK after loads -> 228MB spill).

#define QK2(ST, QA, QB, K0, K1)         \
  do {                                  \
    ST = zero16();                      \
    __builtin_amdgcn_s_setprio(1);      \
    ST = MFMA32(K0, QA, ST);            \
    ST = MFMA32(K1, QB, ST);            \
    __builtin_amdgcn_s_setprio(0);      \
  } while (0)

// softmax chunk (8 S-values starting at LO) + one PV MFMA with VF
#define SM_PV(ST, LO, OACC, LSUM, VF)                                           \
  do {                                                                          \
    float p0_ = EXP2(ST[LO + 0]), p1_ = EXP2(ST[LO + 1]);                       \
    float p2_ = EXP2(ST[LO + 2]), p3_ = EXP2(ST[LO + 3]);                       \
    float p4_ = EXP2(ST[LO + 4]), p5_ = EXP2(ST[LO + 5]);                       \
    float p6_ = EXP2(ST[LO + 6]), p7_ = EXP2(ST[LO + 7]);                       \
    u32 k0_ = pk2(p0_, p1_), k1_ = pk2(p2_, p3_);                               \
    u32 k2_ = pk2(p4_, p5_), k3_ = pk2(p6_, p7_);                               \
    LSUM4(LSUM, k0_, k1_, k2_, k3_)                                             \
    LSUM_F32(LSUM, p0_, p1_, p2_, p3_, p4_, p5_, p6_, p7_)                      \
    u32 ax_ = k0_, bx_ = k2_;                                                   \
    plswap(ax_, bx_);                                                           \
    u32 ay_ = k1_, by_ = k3_;                                                   \
    plswap(ay_, by_);                                                           \
    u32x4v f_;                                                                  \
    f_.x = ax_; f_.y = ay_; f_.z = bx_; f_.w = by_;                             \
    __builtin_amdgcn_s_setprio(1);                                              \
    OACC = MFMA32(VF, __builtin_bit_cast(bf16x8, f_), OACC);                    \
    __builtin_amdgcn_s_setprio(0);                                              \
  } while (0)

// one pipeline stage: consume sTa/sTb for tile tt (V in VF0/VF1), issue QK for tile tt+1 from
// kfn, then refill kfn with K(tt+2) and VF with V(tt+2). Final-iteration dead QK/loads are DCE'd.
#define STAGE(TT, VF0, VF1)                                   \
  do {                                                        \
    SM_PV(sTa, 0, oacc0, lsum0, VF0);                         \
    SM_PV(sTa, 8, oacc0, lsum0, VF1);                         \
    QK2(sTa, qf00, qf01, kfn0, kfn1);                         \
    SM_PV(sTb, 0, oacc1, lsum1, VF0);                         \
    SM_PV(sTb, 8, oacc1, lsum1, VF1);                         \
    QK2(sTb, qf10, qf11, kfn0, kfn1);                         \
    kfn0 = ldfrag(kp0 + (TT + 2) * 1024);                     \
    kfn1 = ldfrag(kp0 + (TT + 2) * 1024 + 16);                \
    VF0 = ldfrag(vp0 + (TT + 2) * 32);                        \
    VF1 = ldfrag(vp0 + (TT + 2) * 32 + 16);                   \
  } while (0)

__global__ __launch_bounds__(512, 4) void attn_fused(const u16* __restrict__ qT,
                                                     const u16* __restrict__ kT,
                                                     const u16* __restrict__ vv,
                                                     u16* __restrict__ aout) {
  __shared__ float pbuf[8 * 32 * 66];  // [8 s][32 c][64 i + 2 pad]
  __shared__ float lbuf[8 * 64];       // [8 s][64 i]
  const int tid = threadIdx.x;
  const int lane = tid & 63, s = tid >> 6;
  const int h = blockIdx.x & 7, qb = blockIdx.x >> 3;  // h -> XCD pinning
  const int l31 = lane & 31, lh = lane >> 5;
  const u16* qTh = qT + (size_t)h * (4096 * 32);
  const u16* kTh = kT + (size_t)h * (4096 * 32);
  const u16* vh = vv + (size_t)h * (32 * 4096);

  // Q fragments (B-operand: col i = l31, k c = m*16+lh*8+e); pre-scaled by SCALE*log2e
  const int i0 = qb * 64 + l31;
  bf16x8 qf00 = ldfrag(qTh + (size_t)i0 * 32 + lh * 8);
  bf16x8 qf01 = ldfrag(qTh + (size_t)i0 * 32 + 16 + lh * 8);
  bf16x8 qf10 = ldfrag(qTh + (size_t)(i0 + 32) * 32 + lh * 8);
  bf16x8 qf11 = ldfrag(qTh + (size_t)(i0 + 32) * 32 + 16 + lh * 8);

  f32x16 oacc0 = zero16(), oacc1 = zero16();
  float lsum0 = 0.0f, lsum1 = 0.0f;
  const int kvbase = s * 512;

  // per-tile bases: K tile tt at kp0 + tt*1024 (u16), V tile tt at vp0 + tt*32
  const u16* kp0 = kTh + (size_t)(kvbase + l31) * 32 + lh * 8;
  const u16* vp0 = vh + (size_t)l31 * 4096 + kvbase + lh * 8;

  // prologue: K/V tile0, K/V tile1; compute sT for tile0
  bf16x8 kc0 = ldfrag(kp0), kc1 = ldfrag(kp0 + 16);
  bf16x8 vfa0 = ldfrag(vp0), vfa1 = ldfrag(vp0 + 16);
  bf16x8 kfn0 = ldfrag(kp0 + 1024), kfn1 = ldfrag(kp0 + 1024 + 16);
  bf16x8 vfb0 = ldfrag(vp0 + 32), vfb1 = ldfrag(vp0 + 32 + 16);
  f32x16 sTa, sTb;
  QK2(sTa, qf00, qf01, kc0, kc1);
  QK2(sTb, qf10, qf11, kc0, kc1);

#pragma unroll
  for (int tt = 0; tt < 16; tt += 2) {
    STAGE(tt, vfa0, vfa1);      // tile tt   (even) — refills vfa with V(tt+2)
    STAGE(tt + 1, vfb0, vfb1);  // tile tt+1 (odd)  — refills vfb with V(tt+3)
  }

  // per-wave partials to LDS (disjoint slots, no atomics)
  float ls0 = lsum0 + __shfl_xor(lsum0, 32, 64);
  float ls1 = lsum1 + __shfl_xor(lsum1, 32, 64);
#pragma unroll
  for (int r = 0; r < 16; ++r) {
    int c = (r & 3) + 8 * (r >> 2) + 4 * lh;
    pbuf[(s * 32 + c) * 66 + l31] = oacc0[r];
    pbuf[(s * 32 + c) * 66 + 32 + l31] = oacc1[r];
  }
  lbuf[s * 64 + l31] = ls0;
  lbuf[s * 64 + 32 + l31] = ls1;
  __syncthreads();

  // reduce 8 kv-split partials, normalize, store attnout[n][256] bf16
  {
    int i = tid >> 3, c0 = (tid & 7) << 2;
    float lt = 0.0f;
#pragma unroll
    for (int ss = 0; ss < 8; ++ss) lt += lbuf[ss * 64 + i];
    float inv = 1.0f / lt;
    float a[4];
#pragma unroll
    for (int cc = 0; cc < 4; ++cc) a[cc] = 0.0f;
#pragma unroll
    for (int ss = 0; ss < 8; ++ss)
#pragma unroll
      for (int cc = 0; cc < 4; ++cc) a[cc] += pbuf[(ss * 32 + c0 + cc) * 66 + i];
    u32x2v ov;
    ov.x = pk2(a[0] * inv, a[1] * inv);
    ov.y = pk2(a[2] * inv, a[3] * inv);
    *(u32x2v*)(aout + (size_t)(qb * 64 + i) * 256 + h * 32 + c0) = ov;
  }
}

// ---------------- K3: out = wob(256x256) @ attnout^T + b, double-buffered counted-vmcnt --------
// grid (64 nb, 4 db); 256 thr = 4 waves, wave w -> d-strip w*16; same 2-phase pipeline as K1
__global__ __launch_bounds__(256) void out_proj(const u16* __restrict__ wob,
                                                const float* __restrict__ bo,
                                                const u16* __restrict__ aout,
                                                float* __restrict__ out) {
  __shared__ __align__(16) u16 Al[2][64 * 64];
  __shared__ __align__(16) u16 Bl[2][64 * 64];
  const int t = threadIdx.x;
  const int lane = t & 63, w = t >> 6;
  const int n0 = blockIdx.x * 64, d0 = blockIdx.y * 64;
  const int lr = lane & 15, lg = lane >> 4;
  const int srow = lane >> 3, sslot = lane & 7;
  f32x4 acc[4];
#pragma unroll
  for (int ni = 0; ni < 4; ++ni)
#pragma unroll
    for (int r = 0; r < 4; ++r) acc[ni][r] = 0.0f;

#define PROJ_STAGE(KI, BUF)                                                                  \
  do {                                                                                       \
    _Pragma("unroll") for (int rnd = 0; rnd < 2; ++rnd) {                                    \
      int row = rnd * 32 + w * 8 + srow;                                                     \
      gload_lds16(wob + (size_t)(d0 + row) * 256 + (KI) * 64 + ((sslot ^ (row & 7)) << 3),   \
                  (void*)(&Al[BUF][rnd * 2048 + w * 512]));                                  \
      gload_lds16(aout + (size_t)(n0 + row) * 256 + (KI) * 64 + ((sslot ^ (row & 7)) << 3),  \
                  (void*)(&Bl[BUF][rnd * 2048 + w * 512]));                                  \
    }                                                                                        \
  } while (0)

  PROJ_STAGE(0, 0);
#pragma unroll
  for (int ki = 0; ki < 4; ++ki) {
    if (ki < 3) {
      PROJ_STAGE(ki + 1, (ki + 1) & 1);
      asm volatile("s_waitcnt vmcnt(4)" ::: "memory");
    } else {
      asm volatile("s_waitcnt vmcnt(0)" ::: "memory");
    }
    __builtin_amdgcn_sched_barrier(0);
    __builtin_amdgcn_s_barrier();
    asm volatile("" ::: "memory");
    const u16* Ab = &Al[ki & 1][0];
    const u16* Bb = &Bl[ki & 1][0];
#pragma unroll
    for (int kk = 0; kk < 2; ++kk) {
      int arow = w * 16 + lr;
      bf16x8 af = ldfrag(&Ab[arow * 64 + ((kk * 32 + lg * 8) ^ ((arow & 7) << 3))]);
#pragma unroll
      for (int ni = 0; ni < 4; ++ni) {
        int brow = ni * 16 + lr;
        bf16x8 bfr = ldfrag(&Bb[brow * 64 + ((kk * 32 + lg * 8) ^ ((brow & 7) << 3))]);
        acc[ni] = MFMA16(af, bfr, acc[ni]);
      }
    }
    asm volatile("s_waitcnt lgkmcnt(0)" ::: "memory");
    __builtin_amdgcn_sched_barrier(0);
    __builtin_amdgcn_s_barrier();
    asm volatile("" ::: "memory");
  }
#pragma unroll
  for (int ni = 0; ni < 4; ++ni) {
    int n = n0 + ni * 16 + lr;
#pragma unroll
    for (int r = 0; r < 4; ++r) {
      int d = d0 + w * 16 + lg * 4 + r;
      out[(size_t)d * 4096 + n] = acc[ni][r] + bo[d];
    }
  }
}

extern "C" void kernel_launch(void* const* d_in, const int* in_sizes, int n_in,
                              void* d_out, int out_size, void* d_ws, size_t ws_size,
                              hipStream_t stream) {
  (void)in_sizes; (void)n_in; (void)out_size; (void)ws_size;
  const float* x = (const float*)d_in[0];
  const float* wqkv = (const float*)d_in[1];
  const float* wout = (const float*)d_in[2];
  const float* bout = (const float*)d_in[3];
  float* out = (float*)d_out;
  u16* qT = (u16*)d_ws;            // [8][4096][32]
  u16* kT = qT + 8 * 4096 * 32;    // [8][4096][32]
  u16* vv = kT + 8 * 4096 * 32;    // [8][32][4096]
  u16* aout = vv + 8 * 32 * 4096;  // [4096][256]
  u16* xT = aout + 4096 * 256;     // [4096][256]
  u16* wqb = xT + 4096 * 256;      // [768][256]
  u16* wob = wqb + 768 * 256;      // [256][256]

  prep<<<320, 256, 0, stream>>>(x, wqkv, wout, xT, wqb, wob);
  qkv_gemm<<<dim3(64, 12), 256, 0, stream>>>(xT, wqb, qT, kT, vv);
  attn_fused<<<512, 512, 0, stream>>>(qT, kT, vv, aout);
  out_proj<<<dim3(64, 4), 256, 0, stream>>>(wob, bout, aout, out);
}